// Round 3
// baseline (253.011 us; speedup 1.0000x reference)
//
#include <hip/hip_runtime.h>
#include <cstdint>

#define DIM 128
#define NCEN 8

constexpr int BLOCK = 256;
constexpr int WAVES = 4;
constexpr int RPG = 4;       // rows per wave-group
constexpr int GROUPS = 4;    // groups per wave
constexpr int ROWS_PER_BLOCK = WAVES * RPG * GROUPS;  // 64

__global__ __launch_bounds__(BLOCK, 2)
void pq_kernel(const float* __restrict__ x,
               const float* __restrict__ Pi,
               const float* __restrict__ cen,
               float* __restrict__ out)
{
    // Pi element (a,b) stored at a*128 + (b ^ (a & 30)); makes both row reads
    // (matmul1, along k) and column-pair reads (matmul2) <=2-way conflicted.
    __shared__ __align__(16) float lds_pi[DIM * DIM];
    __shared__ __align__(16) float xbuf[WAVES][RPG][DIM];
    __shared__ float vn_s[WAVES][RPG];
    __shared__ float vne_s[WAVES][RPG];

    const int tid  = threadIdx.x;
    const int wave = tid >> 6;
    const int lane = tid & 63;

    float cv[NCEN];
#pragma unroll
    for (int i = 0; i < NCEN; ++i) cv[i] = cen[i];

    // ---- stage Pi into LDS, swizzled (values bit-preserved, only permuted) ----
#pragma unroll
    for (int i = 0; i < 16; ++i) {
        int f = tid * 4 + i * (BLOCK * 4);
        int a = f >> 7;
        int b = f & 127;                  // multiple of 4
        float4 v = *reinterpret_cast<const float4*>(Pi + f);
        if (a & 2) v = make_float4(v.z, v.w, v.x, v.y);   // pair swap for xor bit1
        *reinterpret_cast<float4*>(&lds_pi[a * 128 + (b ^ (a & 28))]) = v;
    }
    __syncthreads();

    const int d0 = 2 * lane;                       // this lane's output col pair
    const int ca = d0 & 30;
    const float* prow0 = &lds_pi[(size_t)d0 * 128];
    const float* prow1 = prow0 + 128;

    const int row_block = blockIdx.x * ROWS_PER_BLOCK + wave * (RPG * GROUPS);

    // NOTE: all buffers below are indexed [wave] -> wave-private. CDNA waves are
    // lockstep and same-wave LDS ops complete in order, so no __syncthreads()
    // is needed inside the group loop.
    for (int g = 0; g < GROUPS; ++g) {
        const int r0 = row_block + g * RPG;

        // ---- Phase A: load 4 raw rows of x -> regs + LDS ----
        const int lr   = lane >> 4;
        const int loff = (lane & 15) * 8;
        const float* xp = x + (size_t)(r0 + lr) * DIM + loff;
        float4 va = *reinterpret_cast<const float4*>(xp);
        float4 vb = *reinterpret_cast<const float4*>(xp + 4);
        *reinterpret_cast<float4*>(&xbuf[wave][lr][loff])     = va;
        *reinterpret_cast<float4*>(&xbuf[wave][lr][loff + 4]) = vb;

        // ---- Phase B: f32 norm in numpy pairwise order:
        //      r[j] = x[j]^2 + x[j+8]^2 + ... (16 terms, sequential), then
        //      ((r0+r1)+(r2+r3)) + ((r4+r5)+(r6+r7)); sqrt correctly rounded ----
        if (lane < 32) {
            const int row = lane >> 3;
            const int j   = lane & 7;
            const float* xr_ = &xbuf[wave][row][0];
            float v0 = xr_[j];
            float r  = __fmul_rn(v0, v0);
#pragma unroll
            for (int t = 1; t < 16; ++t) {
                float v = xr_[j + 8 * t];
                r = __fadd_rn(r, __fmul_rn(v, v));
            }
#pragma unroll
            for (int m = 1; m < 8; m <<= 1)
                r = __fadd_rn(r, __shfl_xor(r, m, 64));   // exact numpy combine tree
            if (j == 0) {
                float vn = __fsqrt_rn(r);
                vn_s[wave][row]  = vn;
                vne_s[wave][row] = __fadd_rn(vn, 1e-8f);
            }
        }

        // ---- Phase C: xn = x / (norm + eps), IEEE f32 division; overwrite xbuf ----
        const float vne = vne_s[wave][lr];
        va.x = __fdiv_rn(va.x, vne); va.y = __fdiv_rn(va.y, vne);
        va.z = __fdiv_rn(va.z, vne); va.w = __fdiv_rn(va.w, vne);
        vb.x = __fdiv_rn(vb.x, vne); vb.y = __fdiv_rn(vb.y, vne);
        vb.z = __fdiv_rn(vb.z, vne); vb.w = __fdiv_rn(vb.w, vne);
        *reinterpret_cast<float4*>(&xbuf[wave][lr][loff])     = va;
        *reinterpret_cast<float4*>(&xbuf[wave][lr][loff + 4]) = vb;

        // ---- matmul1: xr[d] = single-accumulator ascending-k FMA chain
        //      (bit-exact vs sgemm microkernel accumulation) ----
        float acc[RPG][2];
#pragma unroll
        for (int r = 0; r < RPG; ++r) { acc[r][0] = 0.f; acc[r][1] = 0.f; }

#pragma unroll 8
        for (int k = 0; k < DIM; k += 4) {
            const int t0 = k ^ ca;
            const int t1 = t0 ^ 2;
            float2 p0a = *reinterpret_cast<const float2*>(prow0 + t0);
            float2 p0b = *reinterpret_cast<const float2*>(prow0 + t1);
            float2 p1a = *reinterpret_cast<const float2*>(prow1 + t0);
            float2 p1b = *reinterpret_cast<const float2*>(prow1 + t1);
#pragma unroll
            for (int r = 0; r < RPG; ++r) {
                float4 xv = *reinterpret_cast<const float4*>(&xbuf[wave][r][k]);
                acc[r][0] = fmaf(xv.x, p0a.x, acc[r][0]);
                acc[r][0] = fmaf(xv.y, p0a.y, acc[r][0]);
                acc[r][0] = fmaf(xv.z, p0b.x, acc[r][0]);
                acc[r][0] = fmaf(xv.w, p0b.y, acc[r][0]);
                acc[r][1] = fmaf(xv.x, p1a.x, acc[r][1]);
                acc[r][1] = fmaf(xv.y, p1a.y, acc[r][1]);
                acc[r][1] = fmaf(xv.z, p1b.x, acc[r][1]);
                acc[r][1] = fmaf(xv.w, p1b.y, acc[r][1]);
            }
        }

        // ---- quantize exactly like reference: argmin over f32 squared
        //      distances (first-min tie-break), sign of f32 residual ----
        float qv[RPG][2], sg[RPG][2], asum[RPG];
#pragma unroll
        for (int r = 0; r < RPG; ++r) {
            asum[r] = 0.f;
#pragma unroll
            for (int j = 0; j < 2; ++j) {
                const float xr = acc[r][j];
                float dd   = __fsub_rn(xr, cv[0]);
                float best = __fmul_rn(dd, dd);
                float q    = cv[0];
#pragma unroll
                for (int i = 1; i < NCEN; ++i) {
                    float di = __fsub_rn(xr, cv[i]);
                    float d2 = __fmul_rn(di, di);
                    if (d2 < best) { best = d2; q = cv[i]; }  // strict <: first-min
                }
                float res = __fsub_rn(xr, q);
                qv[r][j] = q;
                sg[r][j] = (res >= 0.f) ? 1.f : -1.f;
                asum[r] += fabsf(res);
            }
        }

        // ---- residual scale (order-free: smooth path) + write z over xbuf ----
#pragma unroll
        for (int r = 0; r < RPG; ++r) {
            float s = asum[r];
#pragma unroll
            for (int m = 1; m < 64; m <<= 1) s += __shfl_xor(s, m, 64);
            const float sc = s * (1.0f / 128.0f);             // /128 exact
            float z0 = __fadd_rn(qv[r][0], sc * sg[r][0]);    // mul by +-1 exact
            float z1 = __fadd_rn(qv[r][1], sc * sg[r][1]);
            *reinterpret_cast<float2*>(&xbuf[wave][r][d0]) = make_float2(z0, z1);
        }

        // ---- matmul2 (smooth): ascending-d FMA chain, then * vec_norm ----
        float acc2[RPG][2];
#pragma unroll
        for (int r = 0; r < RPG; ++r) { acc2[r][0] = 0.f; acc2[r][1] = 0.f; }

#pragma unroll 8
        for (int d = 0; d < DIM; d += 4) {
            float2 p[4];
#pragma unroll
            for (int i = 0; i < 4; ++i) {
                const int cd = (d + i) & 30;
                p[i] = *reinterpret_cast<const float2*>(&lds_pi[(size_t)(d + i) * 128 + (d0 ^ cd)]);
            }
#pragma unroll
            for (int r = 0; r < RPG; ++r) {
                float4 zv = *reinterpret_cast<const float4*>(&xbuf[wave][r][d]);
                acc2[r][0] = fmaf(zv.x, p[0].x, acc2[r][0]);
                acc2[r][1] = fmaf(zv.x, p[0].y, acc2[r][1]);
                acc2[r][0] = fmaf(zv.y, p[1].x, acc2[r][0]);
                acc2[r][1] = fmaf(zv.y, p[1].y, acc2[r][1]);
                acc2[r][0] = fmaf(zv.z, p[2].x, acc2[r][0]);
                acc2[r][1] = fmaf(zv.z, p[2].y, acc2[r][1]);
                acc2[r][0] = fmaf(zv.w, p[3].x, acc2[r][0]);
                acc2[r][1] = fmaf(zv.w, p[3].y, acc2[r][1]);
            }
        }

#pragma unroll
        for (int r = 0; r < RPG; ++r) {
            const float vnr = vn_s[wave][r];
            float2 o = make_float2(__fmul_rn(acc2[r][0], vnr),
                                   __fmul_rn(acc2[r][1], vnr));
            *reinterpret_cast<float2*>(out + (size_t)(r0 + r) * DIM + d0) = o;
        }
    }
}

extern "C" void kernel_launch(void* const* d_in, const int* in_sizes, int n_in,
                              void* d_out, int out_size, void* d_ws, size_t ws_size,
                              hipStream_t stream) {
    const float* x   = (const float*)d_in[0];
    const float* Pi  = (const float*)d_in[1];
    const float* cen = (const float*)d_in[2];
    float* outp      = (float*)d_out;

    const int n_rows = in_sizes[0] / DIM;
    const int grid   = n_rows / ROWS_PER_BLOCK;

    hipLaunchKernelGGL(pq_kernel, dim3(grid), dim3(BLOCK), 0, stream,
                       x, Pi, cen, outp);
}

// Round 4
// 180.748 us; speedup vs baseline: 1.3998x; 1.3998x over previous
//
#include <hip/hip_runtime.h>
#include <cstdint>

#define DIM 128
#define NCEN 8

constexpr int BLOCK = 512;
constexpr int WAVES = 8;
constexpr int RPG = 4;       // rows per wave-group
constexpr int GROUPS = 4;    // groups per wave
constexpr int ROWS_PER_BLOCK = WAVES * RPG * GROUPS;  // 128

__global__ __launch_bounds__(BLOCK, 4)
void pq_kernel(const float* __restrict__ x,
               const float* __restrict__ Pi,
               const float* __restrict__ cen,
               float* __restrict__ out)
{
    // Pi element (a,b) stored at a*128 + (b ^ (a & 30)); makes both row reads
    // (matmul1, along k) and column-pair reads (matmul2) <=2-way conflicted.
    // LDS total = 64KB (Pi) + 16KB (xbuf) = 80KB exactly -> 2 blocks/CU,
    // 16 waves/CU. vn/vne live in registers + shuffles (NOT LDS) to fit.
    __shared__ __align__(16) float lds_pi[DIM * DIM];
    __shared__ __align__(16) float xbuf[WAVES][RPG][DIM];

    const int tid  = threadIdx.x;
    const int wave = tid >> 6;
    const int lane = tid & 63;

    float cv[NCEN];
#pragma unroll
    for (int i = 0; i < NCEN; ++i) cv[i] = cen[i];

    // ---- stage Pi into LDS, swizzled (values bit-preserved, only permuted) ----
#pragma unroll
    for (int i = 0; i < 8; ++i) {
        int f = tid * 4 + i * (BLOCK * 4);
        int a = f >> 7;
        int b = f & 127;                  // multiple of 4
        float4 v = *reinterpret_cast<const float4*>(Pi + f);
        if (a & 2) v = make_float4(v.z, v.w, v.x, v.y);   // pair swap for xor bit1
        *reinterpret_cast<float4*>(&lds_pi[a * 128 + (b ^ (a & 28))]) = v;
    }
    __syncthreads();

    const int d0 = 2 * lane;                       // this lane's output col pair
    const int ca = d0 & 30;
    const float* prow0 = &lds_pi[(size_t)d0 * 128];
    const float* prow1 = prow0 + 128;

    const int row_block = blockIdx.x * ROWS_PER_BLOCK + wave * (RPG * GROUPS);

    const int lr   = lane >> 4;            // row within group this lane loads
    const int loff = (lane & 15) * 8;      // 8 consecutive elements

    // prologue: load group 0's raw x
    const float* xp0 = x + (size_t)(row_block + lr) * DIM + loff;
    float4 va = *reinterpret_cast<const float4*>(xp0);
    float4 vb = *reinterpret_cast<const float4*>(xp0 + 4);

    // NOTE: xbuf is wave-private and CDNA same-wave LDS ops are ordered, so no
    // __syncthreads() is needed inside the group loop.
    for (int g = 0; g < GROUPS; ++g) {
        const int r0 = row_block + g * RPG;

        // ---- Phase A: raw x -> LDS (for numpy-order norm) ----
        *reinterpret_cast<float4*>(&xbuf[wave][lr][loff])     = va;
        *reinterpret_cast<float4*>(&xbuf[wave][lr][loff + 4]) = vb;

        // ---- Phase B: f32 norm in numpy pairwise order:
        //      r[j] = x[j]^2 + x[j+8]^2 + ... (16 terms, sequential), then
        //      ((r0+r1)+(r2+r3)) + ((r4+r5)+(r6+r7)); sqrt correctly rounded ----
        float vn_l = 0.f, vne_l = 0.f;
        if (lane < 32) {
            const int row = lane >> 3;
            const int j   = lane & 7;
            const float* xr_ = &xbuf[wave][row][0];
            float v0 = xr_[j];
            float r  = __fmul_rn(v0, v0);
#pragma unroll
            for (int t = 1; t < 16; ++t) {
                float v = xr_[j + 8 * t];
                r = __fadd_rn(r, __fmul_rn(v, v));
            }
#pragma unroll
            for (int m = 1; m < 8; m <<= 1)
                r = __fadd_rn(r, __shfl_xor(r, m, 64));   // exact numpy combine tree
            vn_l  = __fsqrt_rn(r);
            vne_l = __fadd_rn(vn_l, 1e-8f);
        }
        // broadcast per-row norm values from lanes {0,8,16,24}
        const float vne = __shfl(vne_l, 8 * lr, 64);

        // ---- Phase C: xn = x / (norm + eps), IEEE f32 division; overwrite xbuf ----
        va.x = __fdiv_rn(va.x, vne); va.y = __fdiv_rn(va.y, vne);
        va.z = __fdiv_rn(va.z, vne); va.w = __fdiv_rn(va.w, vne);
        vb.x = __fdiv_rn(vb.x, vne); vb.y = __fdiv_rn(vb.y, vne);
        vb.z = __fdiv_rn(vb.z, vne); vb.w = __fdiv_rn(vb.w, vne);
        *reinterpret_cast<float4*>(&xbuf[wave][lr][loff])     = va;
        *reinterpret_cast<float4*>(&xbuf[wave][lr][loff + 4]) = vb;

        // ---- prefetch next group's raw x (hides under mm1+quantize+mm2) ----
        float4 va_n = va, vb_n = vb;
        if (g + 1 < GROUPS) {
            const float* xp = x + (size_t)(r0 + RPG + lr) * DIM + loff;
            va_n = *reinterpret_cast<const float4*>(xp);
            vb_n = *reinterpret_cast<const float4*>(xp + 4);
        }

        // ---- matmul1: xr[d] = single-accumulator ascending-k FMA chain
        //      (bit-exact vs sgemm microkernel accumulation) ----
        float acc[RPG][2];
#pragma unroll
        for (int r = 0; r < RPG; ++r) { acc[r][0] = 0.f; acc[r][1] = 0.f; }

#pragma unroll 8
        for (int k = 0; k < DIM; k += 4) {
            const int t0 = k ^ ca;
            const int t1 = t0 ^ 2;
            float2 p0a = *reinterpret_cast<const float2*>(prow0 + t0);
            float2 p0b = *reinterpret_cast<const float2*>(prow0 + t1);
            float2 p1a = *reinterpret_cast<const float2*>(prow1 + t0);
            float2 p1b = *reinterpret_cast<const float2*>(prow1 + t1);
#pragma unroll
            for (int r = 0; r < RPG; ++r) {
                float4 xv = *reinterpret_cast<const float4*>(&xbuf[wave][r][k]);
                acc[r][0] = fmaf(xv.x, p0a.x, acc[r][0]);
                acc[r][0] = fmaf(xv.y, p0a.y, acc[r][0]);
                acc[r][0] = fmaf(xv.z, p0b.x, acc[r][0]);
                acc[r][0] = fmaf(xv.w, p0b.y, acc[r][0]);
                acc[r][1] = fmaf(xv.x, p1a.x, acc[r][1]);
                acc[r][1] = fmaf(xv.y, p1a.y, acc[r][1]);
                acc[r][1] = fmaf(xv.z, p1b.x, acc[r][1]);
                acc[r][1] = fmaf(xv.w, p1b.y, acc[r][1]);
            }
        }

        // ---- quantize exactly like reference: argmin over f32 squared
        //      distances (first-min tie-break), sign of f32 residual ----
        float qv[RPG][2], sg[RPG][2], asum[RPG];
#pragma unroll
        for (int r = 0; r < RPG; ++r) {
            asum[r] = 0.f;
#pragma unroll
            for (int j = 0; j < 2; ++j) {
                const float xr = acc[r][j];
                float dd   = __fsub_rn(xr, cv[0]);
                float best = __fmul_rn(dd, dd);
                float q    = cv[0];
#pragma unroll
                for (int i = 1; i < NCEN; ++i) {
                    float di = __fsub_rn(xr, cv[i]);
                    float d2 = __fmul_rn(di, di);
                    bool  c  = d2 < best;              // strict <: first-min
                    best = c ? d2 : best;
                    q    = c ? cv[i] : q;
                }
                float res = __fsub_rn(xr, q);
                qv[r][j] = q;
                sg[r][j] = (res >= 0.f) ? 1.f : -1.f;
                asum[r] += fabsf(res);
            }
        }

        // ---- residual scale (order-free: smooth path) + write z over xbuf ----
#pragma unroll
        for (int r = 0; r < RPG; ++r) {
            float s = asum[r];
#pragma unroll
            for (int m = 1; m < 64; m <<= 1) s += __shfl_xor(s, m, 64);
            const float sc = s * (1.0f / 128.0f);             // /128 exact
            float z0 = __fadd_rn(qv[r][0], sc * sg[r][0]);    // mul by +-1 exact
            float z1 = __fadd_rn(qv[r][1], sc * sg[r][1]);
            *reinterpret_cast<float2*>(&xbuf[wave][r][d0]) = make_float2(z0, z1);
        }

        // ---- matmul2 (smooth): ascending-d FMA chain, then * vec_norm ----
        float acc2[RPG][2];
#pragma unroll
        for (int r = 0; r < RPG; ++r) { acc2[r][0] = 0.f; acc2[r][1] = 0.f; }

#pragma unroll 8
        for (int d = 0; d < DIM; d += 4) {
            float2 p[4];
#pragma unroll
            for (int i = 0; i < 4; ++i) {
                const int cd = (d + i) & 30;
                p[i] = *reinterpret_cast<const float2*>(&lds_pi[(size_t)(d + i) * 128 + (d0 ^ cd)]);
            }
#pragma unroll
            for (int r = 0; r < RPG; ++r) {
                float4 zv = *reinterpret_cast<const float4*>(&xbuf[wave][r][d]);
                acc2[r][0] = fmaf(zv.x, p[0].x, acc2[r][0]);
                acc2[r][1] = fmaf(zv.x, p[0].y, acc2[r][1]);
                acc2[r][0] = fmaf(zv.y, p[1].x, acc2[r][0]);
                acc2[r][1] = fmaf(zv.y, p[1].y, acc2[r][1]);
                acc2[r][0] = fmaf(zv.z, p[2].x, acc2[r][0]);
                acc2[r][1] = fmaf(zv.z, p[2].y, acc2[r][1]);
                acc2[r][0] = fmaf(zv.w, p[3].x, acc2[r][0]);
                acc2[r][1] = fmaf(zv.w, p[3].y, acc2[r][1]);
            }
        }

#pragma unroll
        for (int r = 0; r < RPG; ++r) {
            const float vnr = __shfl(vn_l, 8 * r, 64);
            float2 o = make_float2(__fmul_rn(acc2[r][0], vnr),
                                   __fmul_rn(acc2[r][1], vnr));
            *reinterpret_cast<float2*>(out + (size_t)(r0 + r) * DIM + d0) = o;
        }

        va = va_n; vb = vb_n;
    }
}

extern "C" void kernel_launch(void* const* d_in, const int* in_sizes, int n_in,
                              void* d_out, int out_size, void* d_ws, size_t ws_size,
                              hipStream_t stream) {
    const float* x   = (const float*)d_in[0];
    const float* Pi  = (const float*)d_in[1];
    const float* cen = (const float*)d_in[2];
    float* outp      = (float*)d_out;

    const int n_rows = in_sizes[0] / DIM;
    const int grid   = n_rows / ROWS_PER_BLOCK;

    hipLaunchKernelGGL(pq_kernel, dim3(grid), dim3(BLOCK), 0, stream,
                       x, Pi, cen, outp);
}

// Round 5
// 122.193 us; speedup vs baseline: 2.0706x; 1.4792x over previous
//
#include <hip/hip_runtime.h>
#include <cstdint>

#define DIM 128
#define NCEN 8

typedef __attribute__((ext_vector_type(8))) short short8;   // 8 bf16 = 4 VGPR
typedef __attribute__((ext_vector_type(4))) float f32x4;

constexpr int BLOCK = 512;
constexpr int WAVES = 8;
constexpr int RPG = 4;       // rows per wave-group
constexpr int GROUPS = 4;    // groups per wave
constexpr int ROWS_PER_BLOCK = WAVES * RPG * GROUPS;  // 128
constexpr int ROW_BYTES = 512;   // one output row slot: 128 f32 (z bf16 in [0,256), vn @256)

__device__ __forceinline__ unsigned bf16rne(float f) {
    unsigned u = __float_as_uint(f);
    return (u + 0x7FFFu + ((u >> 16) & 1u)) >> 16;
}

// ---------------- Phase 1: norm -> rotate (exact f32 chain) -> quantize -> z ----------------
__global__ __launch_bounds__(BLOCK, 4)
void pq_phase1(const float* __restrict__ x,
               const float* __restrict__ Pi,
               const float* __restrict__ cen,
               char* __restrict__ zout)
{
    // Pi element (a,b) stored at a*128 + (b ^ (a & 28)): xor bits 2-4 only, so
    // 4-word groups stay contiguous -> mm1 p-reads are ds_read_b128.
    __shared__ __align__(16) float lds_pi[DIM * DIM];
    __shared__ __align__(16) float xbuf[WAVES][RPG][DIM];

    const int tid  = threadIdx.x;
    const int wave = tid >> 6;
    const int lane = tid & 63;

    float cv[NCEN];
#pragma unroll
    for (int i = 0; i < NCEN; ++i) cv[i] = cen[i];

    // ---- stage Pi into LDS, swizzled (values bit-preserved, only permuted) ----
#pragma unroll
    for (int i = 0; i < 8; ++i) {
        int f = tid * 4 + i * (BLOCK * 4);
        int a = f >> 7;
        int b = f & 127;                  // multiple of 4
        float4 v = *reinterpret_cast<const float4*>(Pi + f);
        *reinterpret_cast<float4*>(&lds_pi[a * 128 + (b ^ (a & 28))]) = v;
    }
    __syncthreads();

    const int d0 = 2 * lane;                       // this lane's column pair
    const int ca = d0 & 28;
    const float* prow0 = &lds_pi[(size_t)d0 * 128];
    const float* prow1 = prow0 + 128;

    const int row_block = blockIdx.x * ROWS_PER_BLOCK + wave * (RPG * GROUPS);

    const int lr   = lane >> 4;            // row within group this lane loads
    const int loff = (lane & 15) * 8;      // 8 consecutive elements

    // prologue: load group 0's raw x
    const float* xp0 = x + (size_t)(row_block + lr) * DIM + loff;
    float4 va = *reinterpret_cast<const float4*>(xp0);
    float4 vb = *reinterpret_cast<const float4*>(xp0 + 4);

    // xbuf is wave-private; CDNA same-wave LDS ops are ordered -> no barriers.
    for (int g = 0; g < GROUPS; ++g) {
        const int r0 = row_block + g * RPG;

        // ---- raw x -> LDS (for numpy-order norm) ----
        *reinterpret_cast<float4*>(&xbuf[wave][lr][loff])     = va;
        *reinterpret_cast<float4*>(&xbuf[wave][lr][loff + 4]) = vb;

        // ---- f32 norm in numpy pairwise order ----
        float vn_l = 0.f, vne_l = 0.f;
        if (lane < 32) {
            const int row = lane >> 3;
            const int j   = lane & 7;
            const float* xr_ = &xbuf[wave][row][0];
            float v0 = xr_[j];
            float r  = __fmul_rn(v0, v0);
#pragma unroll
            for (int t = 1; t < 16; ++t) {
                float v = xr_[j + 8 * t];
                r = __fadd_rn(r, __fmul_rn(v, v));
            }
#pragma unroll
            for (int m = 1; m < 8; m <<= 1)
                r = __fadd_rn(r, __shfl_xor(r, m, 64));   // exact numpy combine tree
            vn_l  = __fsqrt_rn(r);
            vne_l = __fadd_rn(vn_l, 1e-8f);
            if (j == 0)   // store vec_norm for phase 2 (byte 256 of the row slot)
                *reinterpret_cast<float*>(zout + (size_t)(r0 + row) * ROW_BYTES + 256) = vn_l;
        }
        const float vne = __shfl(vne_l, 8 * lr, 64);

        // ---- xn = x / (norm + eps), IEEE f32 division; overwrite xbuf ----
        va.x = __fdiv_rn(va.x, vne); va.y = __fdiv_rn(va.y, vne);
        va.z = __fdiv_rn(va.z, vne); va.w = __fdiv_rn(va.w, vne);
        vb.x = __fdiv_rn(vb.x, vne); vb.y = __fdiv_rn(vb.y, vne);
        vb.z = __fdiv_rn(vb.z, vne); vb.w = __fdiv_rn(vb.w, vne);
        *reinterpret_cast<float4*>(&xbuf[wave][lr][loff])     = va;
        *reinterpret_cast<float4*>(&xbuf[wave][lr][loff + 4]) = vb;

        // ---- prefetch next group's raw x ----
        float4 va_n = va, vb_n = vb;
        if (g + 1 < GROUPS) {
            const float* xp = x + (size_t)(r0 + RPG + lr) * DIM + loff;
            va_n = *reinterpret_cast<const float4*>(xp);
            vb_n = *reinterpret_cast<const float4*>(xp + 4);
        }

        // ---- matmul1: single-accumulator ascending-k FMA chain (bit-exact) ----
        float acc[RPG][2];
#pragma unroll
        for (int r = 0; r < RPG; ++r) { acc[r][0] = 0.f; acc[r][1] = 0.f; }

#pragma unroll 8
        for (int k = 0; k < DIM; k += 4) {
            const int t0 = k ^ ca;
            float4 p0 = *reinterpret_cast<const float4*>(prow0 + t0);
            float4 p1 = *reinterpret_cast<const float4*>(prow1 + t0);
#pragma unroll
            for (int r = 0; r < RPG; ++r) {
                float4 xv = *reinterpret_cast<const float4*>(&xbuf[wave][r][k]);
                acc[r][0] = fmaf(xv.x, p0.x, acc[r][0]);
                acc[r][0] = fmaf(xv.y, p0.y, acc[r][0]);
                acc[r][0] = fmaf(xv.z, p0.z, acc[r][0]);
                acc[r][0] = fmaf(xv.w, p0.w, acc[r][0]);
                acc[r][1] = fmaf(xv.x, p1.x, acc[r][1]);
                acc[r][1] = fmaf(xv.y, p1.y, acc[r][1]);
                acc[r][1] = fmaf(xv.z, p1.z, acc[r][1]);
                acc[r][1] = fmaf(xv.w, p1.w, acc[r][1]);
            }
        }

        // ---- quantize exactly like reference: f32 squared-distance argmin
        //      (first-min tie-break), sign of f32 residual ----
        float qv[RPG][2], sg[RPG][2], asum[RPG];
#pragma unroll
        for (int r = 0; r < RPG; ++r) {
            asum[r] = 0.f;
#pragma unroll
            for (int j = 0; j < 2; ++j) {
                const float xr = acc[r][j];
                float dd   = __fsub_rn(xr, cv[0]);
                float best = __fmul_rn(dd, dd);
                float q    = cv[0];
#pragma unroll
                for (int i = 1; i < NCEN; ++i) {
                    float di = __fsub_rn(xr, cv[i]);
                    float d2 = __fmul_rn(di, di);
                    bool  c  = d2 < best;              // strict <: first-min
                    best = c ? d2 : best;
                    q    = c ? cv[i] : q;
                }
                float res = __fsub_rn(xr, q);
                qv[r][j] = q;
                sg[r][j] = (res >= 0.f) ? 1.f : -1.f;
                asum[r] += fabsf(res);
            }
        }

        // ---- residual scale (order-free) + store z as packed bf16 ----
#pragma unroll
        for (int r = 0; r < RPG; ++r) {
            float s = asum[r];
#pragma unroll
            for (int m = 1; m < 64; m <<= 1) s += __shfl_xor(s, m, 64);
            const float sc = s * (1.0f / 128.0f);             // /128 exact
            float z0 = __fadd_rn(qv[r][0], sc * sg[r][0]);    // mul by +-1 exact
            float z1 = __fadd_rn(qv[r][1], sc * sg[r][1]);
            unsigned pz = bf16rne(z0) | (bf16rne(z1) << 16);
            *reinterpret_cast<unsigned*>(zout + (size_t)(r0 + r) * ROW_BYTES + (size_t)d0 * 2) = pz;
        }

        va = va_n; vb = vb_n;
    }
}

// ---------------- Phase 2: out = (z @ Pi) * vn via bf16 MFMA (smooth path) ----------------
constexpr int BBLOCK = 256;
constexpr int BROWS  = 256;   // rows per block (4 waves x 4 iters x 16 rows)

__global__ __launch_bounds__(BBLOCK, 8)
void pq_phase2(const float* __restrict__ Pi, char* __restrict__ zio)
{
    // piT[n][k] = bf16(Pi[k][n]), element k stored at k ^ ((n&7)<<3)  (T2 swizzle:
    // B-frag reads have 16 lanes at distinct n, same k-range -> 2-way, not 16-way)
    __shared__ __align__(16) unsigned short piT[DIM * DIM];   // 32 KB

    const int tid  = threadIdx.x;
    const int wave = tid >> 6;
    const int lane = tid & 63;

    // ---- stage transposed bf16 Pi (4x4 subtiles per thread) ----
#pragma unroll
    for (int s = 0; s < 4; ++s) {
        int sub = tid + s * BBLOCK;       // 0..1023
        int a4 = (sub & 31) * 4;          // k base
        int b4 = (sub >> 5) * 4;          // n base
        float rv[4][4];
#pragma unroll
        for (int i = 0; i < 4; ++i)
            *reinterpret_cast<float4*>(rv[i]) =
                *reinterpret_cast<const float4*>(Pi + (size_t)(a4 + i) * DIM + b4);
#pragma unroll
        for (int j = 0; j < 4; ++j) {
            const int n   = b4 + j;
            const int ksw = a4 ^ ((n & 7) << 3);   // xor bits 3-5: keeps 4-chunk intact
            unsigned lo = bf16rne(rv[0][j]) | (bf16rne(rv[1][j]) << 16);
            unsigned hi = bf16rne(rv[2][j]) | (bf16rne(rv[3][j]) << 16);
            *reinterpret_cast<uint2*>(&piT[n * DIM + ksw]) = make_uint2(lo, hi);
        }
    }
    __syncthreads();

    const int rowbase0 = blockIdx.x * BROWS;

    for (int it = 0; it < BROWS / 64; ++it) {      // 4 iterations
        const int rowbase = rowbase0 + it * 64 + wave * 16;

        // A-frags: lane holds row (lane&15), k = (lane>>4)*8 + j + 32*kf
        const char* zr = zio + (size_t)(rowbase + (lane & 15)) * ROW_BYTES + ((lane >> 4) * 16);
        short8 afr[4];
#pragma unroll
        for (int kf = 0; kf < 4; ++kf)
            afr[kf] = *reinterpret_cast<const short8*>(zr + kf * 64);

        // vn for this lane's 4 output rows: m = (lane>>4)*4 + q
        float vnr[4];
#pragma unroll
        for (int q = 0; q < 4; ++q)
            vnr[q] = *reinterpret_cast<const float*>(
                zio + (size_t)(rowbase + (lane >> 4) * 4 + q) * ROW_BYTES + 256);

#pragma unroll
        for (int nt = 0; nt < 8; ++nt) {
            const int n = nt * 16 + (lane & 15);
            f32x4 acc = {0.f, 0.f, 0.f, 0.f};
#pragma unroll
            for (int kf = 0; kf < 4; ++kf) {
                const int k0  = kf * 32 + (lane >> 4) * 8;
                const int ksw = k0 ^ ((n & 7) << 3);
                short8 bfr = *reinterpret_cast<const short8*>(&piT[n * DIM + ksw]);
                acc = __builtin_amdgcn_mfma_f32_16x16x32_bf16(afr[kf], bfr, acc, 0, 0, 0);
            }
            // C/D: col = lane&15, row = (lane>>4)*4 + q   [guide m89, verified]
#pragma unroll
            for (int q = 0; q < 4; ++q) {
                float o = __fmul_rn(acc[q], vnr[q]);
                *reinterpret_cast<float*>(
                    zio + (size_t)(rowbase + (lane >> 4) * 4 + q) * ROW_BYTES
                        + (size_t)(nt * 16 + (lane & 15)) * 4) = o;
            }
        }
    }
}

extern "C" void kernel_launch(void* const* d_in, const int* in_sizes, int n_in,
                              void* d_out, int out_size, void* d_ws, size_t ws_size,
                              hipStream_t stream) {
    const float* x   = (const float*)d_in[0];
    const float* Pi  = (const float*)d_in[1];
    const float* cen = (const float*)d_in[2];
    char* outp       = (char*)d_out;

    const int n_rows = in_sizes[0] / DIM;

    hipLaunchKernelGGL(pq_phase1, dim3(n_rows / ROWS_PER_BLOCK), dim3(BLOCK), 0, stream,
                       x, Pi, cen, outp);
    hipLaunchKernelGGL(pq_phase2, dim3(n_rows / BROWS), dim3(BBLOCK), 0, stream,
                       Pi, outp);
}